// Round 6
// baseline (11834.453 us; speedup 1.0000x reference)
//
#include <hip/hip_runtime.h>
#include <hip/hip_bf16.h>

// ---------------------------------------------------------------------------
// 3-layer original-paper GRU, B=128, T=128, I=512, H={512,1024,2048}.
// Round 11: persistent kernel v2 -- R9 with the barrier replaced.
//  - R9 counters: MfmaUtil 2.6%, compute ~26us/tick but tick=95us ->
//    ~34us PER BARRIER. Cause: 224 serialized atomicAdd RMWs on ONE line at
//    the cross-XCD coherence point + single-line polling.
//  - Fix: FLAG-ARRAY barrier. Each block stores its epoch to its own 128B
//    line (parallel, no RMW; __syncthreads already drained vmcnt so all sc1
//    data stores are at the coherence point). First NBLK threads of every
//    block poll distinct flag lines; one acquire fence per round.
//  - Everything else byte-identical to R9 (proven correct): sc1 agent stores
//    for cross-block tensors, hf/out block-private via role alignment,
//    R6's proven 2-buffer BK=128 GEMM engine (R8/R10 pipeline attempts both
//    regressed -- engine is final).
// ---------------------------------------------------------------------------

typedef __attribute__((ext_vector_type(8))) short s16x8;
typedef __attribute__((ext_vector_type(4))) float f32x4;

#define NBLK 224

#define LLDS16(g, s)                                                          \
  __builtin_amdgcn_global_load_lds(                                           \
      (const __attribute__((address_space(1))) void*)(g),                     \
      (__attribute__((address_space(3))) void*)(s), 16, 0, 0)

__device__ __forceinline__ unsigned short f2b(float f) {
  unsigned int u = __float_as_uint(f);
  unsigned int r = (u + 0x7FFFu + ((u >> 16) & 1u)) >> 16;
  return (unsigned short)r;
}
__device__ __forceinline__ float sigmoidf_(float x) {
  return 1.0f / (1.0f + __expf(-x));
}
__device__ __forceinline__ float tanhf_(float x) {
  x = fminf(fmaxf(x, -15.0f), 15.0f);
  float e = __expf(-2.0f * x);
  return (1.0f - e) / (1.0f + e);
}

struct DiagP {
  const unsigned short* xb;            // [B,T,I] bf16
  const unsigned short* wihzr0;        // [2*512, 512]
  const unsigned short* wihn0;         // [512, 512]
  const unsigned short* wihF[3];       // full [3H, inl] (l=1,2 used)
  const unsigned short* whhzr[3];      // [2H, H]
  const unsigned short* whhn[3];       // [H, H]
  const float* bias[3];                // [3H]
  float* hf[3][2];                     // f32 h, 2 slots (tick parity) PRIVATE
  unsigned short* hb[3][2];            // bf16 h, 2 slots (agent stores)
  float* zb[3];                        // [B,H] f32 (agent stores)
  unsigned short* rh[3];               // [B,H] bf16 (agent stores)
  float* gi[3][2];                     // [B,3H] f32, 2 slots (agent stores)
  const float* mask;                   // [B,T]
  float* out;                          // [B,3584] PRIVATE RMW
  int* flags;                          // NBLK flags, 128B apart
};

// ---- agent-scope helpers ---------------------------------------------------
__device__ __forceinline__ void stf_agent(float* p, float v) {
  __hip_atomic_store(p, v, __ATOMIC_RELAXED, __HIP_MEMORY_SCOPE_AGENT);
}
// lane-pair packed bf16 store: lanes (2k,2k+1) hold adjacent cols; even lane
// stores both as one 4B agent store. idx must be the even lane's index.
__device__ __forceinline__ void st_bf16_pair(unsigned short* base, size_t idx,
                                             unsigned short mine, int l16) {
  unsigned int other = __shfl_xor((unsigned int)mine, 1);
  if (!(l16 & 1))
    __hip_atomic_store((unsigned int*)(base + idx),
                       (unsigned int)mine | (other << 16), __ATOMIC_RELAXED,
                       __HIP_MEMORY_SCOPE_AGENT);
}

// ---- flag-array barrier: parallel arrivals, distributed polling -----------
// Correctness: __syncthreads drains each wave's vmcnt, so every thread's sc1
// stores have reached the coherence point before the flag store (R9-proven
// semantics). Poll condition >= ep tolerates blocks 1 round ahead.
__device__ __forceinline__ void gbar(int* flags, int ep) {
  __syncthreads();
  if (threadIdx.x == 0)
    __hip_atomic_store(flags + (size_t)blockIdx.x * 32, ep, __ATOMIC_RELAXED,
                       __HIP_MEMORY_SCOPE_AGENT);
  if (threadIdx.x < NBLK) {
    while (__hip_atomic_load(flags + (size_t)threadIdx.x * 32,
                             __ATOMIC_RELAXED,
                             __HIP_MEMORY_SCOPE_AGENT) < ep)
      __builtin_amdgcn_s_sleep(1);
  }
  __syncthreads();
  __builtin_amdgcn_fence(__ATOMIC_ACQUIRE, "agent");  // inv stale L1/L2
}

// ---- staging: 128x128 A tile (32 KB) and 64x128 B tile (16 KB), swizzled --
__device__ __forceinline__ void stageA(const unsigned short* __restrict__ g,
                                       size_t ld, int k0, unsigned short* lds) {
  const int tid = threadIdx.x;
  const int wave = tid >> 6, lane = tid & 63;
#pragma unroll
  for (int j = 0; j < 4; ++j) {
    int s = wave * 4 + j;             // 0..31, 1 KB segments (4 rows)
    int r = s * 4 + (lane >> 4);      // 0..127
    int cg = (lane & 15) ^ (r & 15);
    LLDS16(g + (size_t)r * ld + k0 + cg * 8, lds + s * 512);
  }
}
__device__ __forceinline__ void stageB(const unsigned short* __restrict__ g,
                                       size_t ld, int rowbase, int k0,
                                       unsigned short* lds) {
  const int tid = threadIdx.x;
  const int wave = tid >> 6, lane = tid & 63;
#pragma unroll
  for (int j = 0; j < 2; ++j) {
    int s = wave * 2 + j;             // 0..15
    int r = s * 4 + (lane >> 4);      // 0..63
    int cg = (lane & 15) ^ (r & 15);
    LLDS16(g + (size_t)(rowbase + r) * ld + k0 + cg * 8, lds + s * 512);
  }
}

// ---- one BK=128 chunk: wave (wr,wcp) rows wr*32+[0,32), cols wcp*32+[0,32)
__device__ __forceinline__ void cchunk(const unsigned short* Ab,
                                       const unsigned short* Bb,
                                       f32x4 acc[2][2]) {
  const int tid = threadIdx.x;
  const int wave = tid >> 6, lane = tid & 63;
  const int wr = wave >> 1, wcp = wave & 1, quad = lane >> 4, l16 = lane & 15;
#pragma unroll
  for (int ks = 0; ks < 4; ++ks) {
    int kg = ks * 4 + quad;
    s16x8 bv[2], av[2];
#pragma unroll
    for (int ni = 0; ni < 2; ++ni) {
      int brow = wcp * 32 + ni * 16 + l16;
      bv[ni] =
          *(const s16x8*)(Bb + (size_t)brow * 128 + ((kg ^ (brow & 15)) * 8));
    }
#pragma unroll
    for (int mi = 0; mi < 2; ++mi) {
      int r = wr * 32 + mi * 16 + l16;
      av[mi] =
          *(const s16x8*)(Ab + (size_t)r * 128 + ((kg ^ (r & 15)) * 8));
    }
#pragma unroll
    for (int mi = 0; mi < 2; ++mi)
#pragma unroll
      for (int ni = 0; ni < 2; ++ni)
        acc[mi][ni] = __builtin_amdgcn_mfma_f32_16x16x32_bf16(
            av[mi], bv[ni], acc[mi][ni], 0, 0, 0);
  }
}

// acc += A1@B1^T (c1 chunks) + A2@B2^T (c2 chunks); B rows at rowbase.
__device__ __forceinline__ void gemm_diag(
    const unsigned short* __restrict__ A1, size_t ldA1, int c1,
    const unsigned short* __restrict__ A2, size_t ldA2, int c2,
    const unsigned short* __restrict__ B1, size_t ldB1,
    const unsigned short* __restrict__ B2, size_t ldB2, int rowbase,
    unsigned short* As, unsigned short* Bs, f32x4 acc[2][2]) {
  const int total = c1 + c2;
  auto issue = [&](int c, int buf) {
    unsigned short* a = As + buf * 16384;
    unsigned short* b = Bs + buf * 8192;
    if (c < c1) {
      stageA(A1, ldA1, c << 7, a);
      stageB(B1, ldB1, rowbase, c << 7, b);
    } else {
      int k0 = (c - c1) << 7;
      stageA(A2, ldA2, k0, a);
      stageB(B2, ldB2, rowbase, k0, b);
    }
  };
  issue(0, 0);
#pragma unroll 1
  for (int c = 0; c < total; ++c) {
    __syncthreads();  // drains vmcnt: chunk c resident; WAR-protects buffers
    if (c + 1 < total) issue(c + 1, (c + 1) & 1);
    cchunk(As + (c & 1) * 16384, Bs + (c & 1) * 8192, acc);
  }
}

// ---------------------------------------------------------------------------
// Persistent kernel. 224 blocks, 1/CU.
// ZR round roles:  blk 0..15 -> L0 tiles, 16..47 -> L1, 48..111 -> L2.
// N round roles:   n(0,nt)=blk 8+nt; n(1,nt)=32+nt; n(2,nt)=80+nt
//                  (== zr r-half blocks so hf stays private);
//                  gi1 g0..47 = blk 112..159; gi2 g0..63 = 160..223,
//                  g64..95 = blk 48..79.
// ---------------------------------------------------------------------------
__global__ __launch_bounds__(512, 2) void diag_all(DiagP p) {
  __shared__ unsigned short As[2 * 16384], Bs[2 * 8192];
  const int blk = blockIdx.x, tid = threadIdx.x;
  const int wave = tid >> 6, lane = tid & 63;
  const int wr = wave >> 1, wcp = wave & 1, quad = lane >> 4, l16 = lane & 15;
  int ep = 0;

#pragma unroll 1
  for (int u = 0; u < 132; ++u) {
    const int oldS = (u + 1) & 1, newS = u & 1;

    // ================= ZR round =================
    if (blk < 112) {
      const int l = (blk < 16) ? 0 : ((blk < 48) ? 1 : 2);
      const int nt = blk - ((l == 0) ? 0 : ((l == 1) ? 16 : 48));
      const int t = u - 2 * l;
      if (t >= 0 && t < 128) {
        const int H = 512 << l;
        f32x4 acc[2][2] = {};
        if (l == 0)
          gemm_diag(p.xb + (size_t)t * 512, (size_t)128 * 512, 4,
                    p.hb[0][oldS], 512, 4, p.wihzr0, 512, p.whhzr[0], 512,
                    nt * 64, As, Bs, acc);
        else
          gemm_diag(p.hb[l][oldS], (size_t)H, H >> 7,
                    (const unsigned short*)0, 0, 0, p.whhzr[l], (size_t)H,
                    (const unsigned short*)0, 0, nt * 64, As, Bs, acc);

        const float* hfo = p.hf[l][oldS];  // private (r-half == n block)
        const float* gil = (l == 0) ? (const float*)0 : p.gi[l][t & 1];
#pragma unroll
        for (int ni = 0; ni < 2; ++ni) {
          const int colg = nt * 64 + wcp * 32 + ni * 16 + l16;
          const float bv = p.bias[l][colg];
          const bool isz = colg < H;  // uniform per block
          const int j = isz ? colg : colg - H;
#pragma unroll
          for (int mi = 0; mi < 2; ++mi)
#pragma unroll
            for (int r = 0; r < 4; ++r) {
              const int row = wr * 32 + mi * 16 + quad * 4 + r;
              float v = acc[mi][ni][r] + bv;
              if (l) v += gil[(size_t)row * 3 * H + colg];
              float s = sigmoidf_(v);
              if (isz) {
                stf_agent(&p.zb[l][(size_t)row * H + j], s);
              } else {
                unsigned short m = f2b(s * hfo[(size_t)row * H + j]);
                st_bf16_pair(p.rh[l], (size_t)row * H + (j & ~1), m, l16);
              }
            }
        }
      }
    }
    gbar(p.flags, ++ep);

    // ================= N round =================
    {
      int role = -1, l = 0, nt = 0, g = 0;
      if (blk >= 8 && blk < 16) { role = 0; l = 0; nt = blk - 8; }
      else if (blk >= 32 && blk < 48) { role = 0; l = 1; nt = blk - 32; }
      else if (blk >= 80 && blk < 112) { role = 0; l = 2; nt = blk - 80; }
      else if (blk >= 112 && blk < 160) { role = 1; g = blk - 112; }
      else if (blk >= 160) { role = 2; g = blk - 160; }
      else if (blk >= 48 && blk < 80) { role = 2; g = 64 + (blk - 48); }

      if (role == 0) {
        const int t = u - 2 * l;
        if (t >= 0 && t < 128) {
          const int H = 512 << l;
          const int outoff = (l == 0) ? 0 : ((l == 1) ? 512 : 1536);
          f32x4 acc[2][2] = {};
          if (l == 0)
            gemm_diag(p.xb + (size_t)t * 512, (size_t)128 * 512, 4, p.rh[0],
                      512, 4, p.wihn0, 512, p.whhn[0], 512, nt * 64, As, Bs,
                      acc);
          else
            gemm_diag(p.rh[l], (size_t)H, H >> 7, (const unsigned short*)0, 0,
                      0, p.whhn[l], (size_t)H, (const unsigned short*)0, 0,
                      nt * 64, As, Bs, acc);

          const float* hfo = p.hf[l][oldS];   // private
          float* hfn = p.hf[l][newS];         // private
          unsigned short* hbn = p.hb[l][newS];
          const float* gil =
              (l == 0) ? (const float*)0 : (p.gi[l][t & 1] + 2 * H);
#pragma unroll
          for (int ni = 0; ni < 2; ++ni) {
            const int colg = nt * 64 + wcp * 32 + ni * 16 + l16;
            const float bv = p.bias[l][2 * H + colg];
#pragma unroll
            for (int mi = 0; mi < 2; ++mi)
#pragma unroll
              for (int r = 0; r < 4; ++r) {
                const int row = wr * 32 + mi * 16 + quad * 4 + r;
                float v = acc[mi][ni][r] + bv;
                if (l) v += gil[(size_t)row * 3 * H + colg];
                float nv = tanhf_(v);
                size_t idx = (size_t)row * H + colg;
                float z = p.zb[l][idx];  // post-fence plain read
                float hn = (1.0f - z) * nv + z * hfo[idx];
                hfn[idx] = hn;  // private
                st_bf16_pair(hbn, (size_t)row * H + (colg & ~1), f2b(hn), l16);
                p.out[(size_t)row * 3584 + outoff + colg] +=
                    p.mask[row * 128 + t] * hn;  // private RMW
              }
          }
        }
      } else if (role == 1) {
        const int tg = u - 1;
        if (tg >= 0 && tg < 128) {
          f32x4 acc[2][2] = {};
          gemm_diag(p.hb[0][oldS], 512, 4, (const unsigned short*)0, 0, 0,
                    p.wihF[1], 512, (const unsigned short*)0, 0, g * 64, As,
                    Bs, acc);
          float* gd = p.gi[1][tg & 1];
#pragma unroll
          for (int ni = 0; ni < 2; ++ni)
#pragma unroll
            for (int mi = 0; mi < 2; ++mi)
#pragma unroll
              for (int rr = 0; rr < 4; ++rr) {
                int row = wr * 32 + mi * 16 + quad * 4 + rr;
                int colg = g * 64 + wcp * 32 + ni * 16 + l16;
                stf_agent(&gd[(size_t)row * 3072 + colg], acc[mi][ni][rr]);
              }
        }
      } else if (role == 2) {
        const int tg = u - 3;
        if (tg >= 0 && tg < 128) {
          f32x4 acc[2][2] = {};
          gemm_diag(p.hb[1][oldS], 1024, 8, (const unsigned short*)0, 0, 0,
                    p.wihF[2], 1024, (const unsigned short*)0, 0, g * 64, As,
                    Bs, acc);
          float* gd = p.gi[2][tg & 1];
#pragma unroll
          for (int ni = 0; ni < 2; ++ni)
#pragma unroll
            for (int mi = 0; mi < 2; ++mi)
#pragma unroll
              for (int rr = 0; rr < 4; ++rr) {
                int row = wr * 32 + mi * 16 + quad * 4 + rr;
                int colg = g * 64 + wcp * 32 + ni * 16 + l16;
                stf_agent(&gd[(size_t)row * 6144 + colg], acc[mi][ni][rr]);
              }
        }
      }
    }
    gbar(p.flags, ++ep);
  }
}

__global__ void cast_kernel(const float* __restrict__ src,
                            unsigned short* __restrict__ dst, int n) {
  int i = blockIdx.x * 256 + threadIdx.x;
  if (i < n) dst[i] = f2b(src[i]);
}

extern "C" void kernel_launch(void* const* d_in, const int* in_sizes, int n_in,
                              void* d_out, int out_size, void* d_ws,
                              size_t ws_size, hipStream_t stream) {
  const int B = 128, T = 128, I = 512;
  const int Hs[3] = {512, 1024, 2048};

  const float* x = (const float*)d_in[0];
  const float* mask = (const float*)d_in[1];
  const float* Wih[3] = {(const float*)d_in[2], (const float*)d_in[5],
                         (const float*)d_in[8]};
  const float* Whh[3] = {(const float*)d_in[3], (const float*)d_in[6],
                         (const float*)d_in[9]};
  const float* bias[3] = {(const float*)d_in[4], (const float*)d_in[7],
                          (const float*)d_in[10]};

  char* ws = (char*)d_ws;
  size_t off = 0;
  auto alloc = [&](size_t bytes) -> void* {
    void* p = ws + off;
    off = (off + bytes + 255) & ~(size_t)255;
    return p;
  };

  unsigned short* xb = (unsigned short*)alloc((size_t)B * T * I * 2);
  unsigned short *wihb[3], *whhb[3];
  for (int l = 0; l < 3; ++l) {
    int inl = (l == 0) ? I : Hs[l - 1];
    wihb[l] = (unsigned short*)alloc((size_t)3 * Hs[l] * inl * 2);
    whhb[l] = (unsigned short*)alloc((size_t)3 * Hs[l] * Hs[l] * 2);
  }
  size_t hstart = off;
  DiagP p;
  for (int l = 0; l < 3; ++l)
    for (int sl = 0; sl < 2; ++sl)
      p.hf[l][sl] = (float*)alloc((size_t)B * Hs[l] * 4);
  for (int l = 0; l < 3; ++l)
    for (int sl = 0; sl < 2; ++sl)
      p.hb[l][sl] = (unsigned short*)alloc((size_t)B * Hs[l] * 2);
  size_t hend = off;
  for (int l = 0; l < 3; ++l) p.zb[l] = (float*)alloc((size_t)B * Hs[l] * 4);
  for (int l = 0; l < 3; ++l)
    p.rh[l] = (unsigned short*)alloc((size_t)B * Hs[l] * 2);
  p.gi[0][0] = p.gi[0][1] = (float*)0;
  for (int l = 1; l < 3; ++l)
    for (int sl = 0; sl < 2; ++sl)
      p.gi[l][sl] = (float*)alloc((size_t)B * 3 * Hs[l] * 4);
  p.flags = (int*)alloc((size_t)NBLK * 32 * 4);
  (void)ws_size;

  p.xb = xb;
  p.wihzr0 = wihb[0];
  p.wihn0 = wihb[0] + (size_t)2 * Hs[0] * I;
  for (int l = 0; l < 3; ++l) {
    p.wihF[l] = wihb[l];
    p.whhzr[l] = whhb[l];
    p.whhn[l] = whhb[l] + (size_t)2 * Hs[l] * Hs[l];
    p.bias[l] = bias[l];
  }
  p.mask = mask;
  p.out = (float*)d_out;

  auto cast = [&](const float* s, unsigned short* d, int n) {
    cast_kernel<<<(n + 255) / 256, 256, 0, stream>>>(s, d, n);
  };
  cast(x, xb, B * T * I);
  for (int l = 0; l < 3; ++l) {
    int inl = (l == 0) ? I : Hs[l - 1];
    cast(Wih[l], wihb[l], 3 * Hs[l] * inl);
    cast(Whh[l], whhb[l], 3 * Hs[l] * Hs[l]);
  }
  hipMemsetAsync(ws + hstart, 0, hend - hstart, stream);
  hipMemsetAsync(p.flags, 0, (size_t)NBLK * 32 * 4, stream);
  hipMemsetAsync(d_out, 0, (size_t)out_size * 4, stream);

  // ---- one persistent kernel: all 132 ticks, 264 internal barriers ----
  diag_all<<<NBLK, 512, 0, stream>>>(p);
}

// Round 7
// 6862.386 us; speedup vs baseline: 1.7245x; 1.7245x over previous
//
#include <hip/hip_runtime.h>
#include <hip/hip_bf16.h>

// ---------------------------------------------------------------------------
// 3-layer original-paper GRU, B=128, T=128, I=512, H={512,1024,2048}.
// Round 12: R6 schedule + small tiles for 3-blocks/CU co-residency.
//  - R9/R11 persistent: ~30us/global-barrier regardless of impl -> dead.
//  - R6's 0.79us/48KB chunk = latency exposure at 1 block/CU (96KB LDS):
//    every __syncthreads vmcnt(0) drain idles the CU. Fix per m114: get
//    co-resident blocks, not source pipelining (R8/R10 both regressed).
//  - Tiles: M=64 (batch split mh) x N=32, BK=128, 128 thr (2 waves),
//    LDS 48KB -> 3 blocks/CU. Engine/sync byte-identical otherwise.
//  - zr launch (640 blk): zr-gates (224 roles) + gi1 (96 roles), x2 mh.
//    gi(1,u-1) moved here: needs only h0(u-1) from previous launch.
//  - n launch (608 blk): n-gates (112 roles) + gi2 (192 roles), x2 mh.
//  - mh pair (role, role+R), R%8==0 -> same XCD -> weight L2 reuse.
//  - Coherence purely via kernel boundaries (plain stores, like R6).
// ---------------------------------------------------------------------------

typedef __attribute__((ext_vector_type(8))) short s16x8;
typedef __attribute__((ext_vector_type(4))) float f32x4;

#define LLDS16(g, s)                                                          \
  __builtin_amdgcn_global_load_lds(                                           \
      (const __attribute__((address_space(1))) void*)(g),                     \
      (__attribute__((address_space(3))) void*)(s), 16, 0, 0)

__device__ __forceinline__ unsigned short f2b(float f) {
  unsigned int u = __float_as_uint(f);
  unsigned int r = (u + 0x7FFFu + ((u >> 16) & 1u)) >> 16;
  return (unsigned short)r;
}
__device__ __forceinline__ float sigmoidf_(float x) {
  return 1.0f / (1.0f + __expf(-x));
}
__device__ __forceinline__ float tanhf_(float x) {
  x = fminf(fmaxf(x, -15.0f), 15.0f);
  float e = __expf(-2.0f * x);
  return (1.0f - e) / (1.0f + e);
}

struct DiagP {
  const unsigned short* xb;            // [B,T,I] bf16
  const unsigned short* wihzr0;        // [2*512, 512]
  const unsigned short* wihn0;         // [512, 512]
  const unsigned short* wihF[3];       // full [3H, inl] (l=1,2 used)
  const unsigned short* whhzr[3];      // [2H, H]
  const unsigned short* whhn[3];       // [H, H]
  const float* bias[3];                // [3H]
  float* hf[3][2];                     // f32 h, 2 slots (tick parity)
  unsigned short* hb[3][2];            // bf16 h, 2 slots
  float* zb[3];                        // [B,H] f32
  unsigned short* rh[3];               // [B,H] bf16
  float* gi[3][2];                     // [B,3H] f32, 2 slots (t parity)
  const float* mask;                   // [B,T]
  float* out;                          // [B,3584]
};

// ---- staging (128 threads): A tile 64x128 (16KB), B tile 32x128 (8KB) -----
// LDS row r at r*256B; 16B granule cg holds source col-group cg^(r&15).
__device__ __forceinline__ void stageA(const unsigned short* __restrict__ g,
                                       size_t ld, int k0, unsigned short* lds) {
  const int tid = threadIdx.x;
#pragma unroll
  for (int j = 0; j < 8; ++j) {
    int idx = j * 128 + tid;          // 0..1023 granules
    int r = idx >> 4;                 // 0..63
    int cg = (idx & 15) ^ (r & 15);
    LLDS16(g + (size_t)r * ld + k0 + cg * 8, lds + idx * 8);
  }
}
__device__ __forceinline__ void stageB(const unsigned short* __restrict__ g,
                                       size_t ld, int rowbase, int k0,
                                       unsigned short* lds) {
  const int tid = threadIdx.x;
#pragma unroll
  for (int j = 0; j < 4; ++j) {
    int idx = j * 128 + tid;          // 0..511 granules
    int r = idx >> 4;                 // 0..31
    int cg = (idx & 15) ^ (r & 15);
    LLDS16(g + (size_t)(rowbase + r) * ld + k0 + cg * 8, lds + idx * 8);
  }
}

// ---- one BK=128 chunk: wave w computes rows w*32+[0,32), cols [0,32) ------
__device__ __forceinline__ void cchunk(const unsigned short* Ab,
                                       const unsigned short* Bb,
                                       f32x4 acc[2][2]) {
  const int tid = threadIdx.x;
  const int wave = tid >> 6, lane = tid & 63;
  const int quad = lane >> 4, l16 = lane & 15;
#pragma unroll
  for (int ks = 0; ks < 4; ++ks) {
    int kg = ks * 4 + quad;
    s16x8 bv[2], av[2];
#pragma unroll
    for (int ni = 0; ni < 2; ++ni) {
      int br = ni * 16 + l16;
      bv[ni] =
          *(const s16x8*)(Bb + (size_t)br * 128 + ((kg ^ (br & 15)) * 8));
    }
#pragma unroll
    for (int mi = 0; mi < 2; ++mi) {
      int ar = wave * 32 + mi * 16 + l16;
      av[mi] =
          *(const s16x8*)(Ab + (size_t)ar * 128 + ((kg ^ (ar & 15)) * 8));
    }
#pragma unroll
    for (int mi = 0; mi < 2; ++mi)
#pragma unroll
      for (int ni = 0; ni < 2; ++ni)
        acc[mi][ni] = __builtin_amdgcn_mfma_f32_16x16x32_bf16(
            av[mi], bv[ni], acc[mi][ni], 0, 0, 0);
  }
}

// acc += A1@B1^T (c1 chunks) + A2@B2^T (c2 chunks); B rows at rowbase.
// Proven 2-buffer engine (R6): __syncthreads drains vmcnt per chunk; the
// latency it exposes is hidden by the 2 other co-resident blocks on the CU.
__device__ __forceinline__ void gemm_diag(
    const unsigned short* __restrict__ A1, size_t ldA1, int c1,
    const unsigned short* __restrict__ A2, size_t ldA2, int c2,
    const unsigned short* __restrict__ B1, size_t ldB1,
    const unsigned short* __restrict__ B2, size_t ldB2, int rowbase,
    unsigned short* As, unsigned short* Bs, f32x4 acc[2][2]) {
  const int total = c1 + c2;
  auto issue = [&](int c, int buf) {
    unsigned short* a = As + buf * 8192;
    unsigned short* b = Bs + buf * 4096;
    if (c < c1) {
      stageA(A1, ldA1, c << 7, a);
      stageB(B1, ldB1, rowbase, c << 7, b);
    } else {
      int k0 = (c - c1) << 7;
      stageA(A2, ldA2, k0, a);
      stageB(B2, ldB2, rowbase, k0, b);
    }
  };
  issue(0, 0);
#pragma unroll 1
  for (int c = 0; c < total; ++c) {
    __syncthreads();  // drains vmcnt: chunk c resident; WAR-protects buffers
    if (c + 1 < total) issue(c + 1, (c + 1) & 1);
    cchunk(As + (c & 1) * 8192, Bs + (c & 1) * 4096, acc);
  }
}

// ---- zr launch: zr-gates + gi1. Grid 640 = 2*(224+96). -------------------
// role<224: zr(l,nt): l0 nt 0..31, l1 0..63, l2 0..127. role>=224: gi1 g.
__global__ __launch_bounds__(128) void diag_zr(DiagP p, int u) {
  __shared__ unsigned short As[2 * 8192], Bs[2 * 4096];
  const int blk = blockIdx.x;
  const int mh = (blk >= 320) ? 1 : 0;
  const int role = blk - 320 * mh;
  const int tid = threadIdx.x, wave = tid >> 6, lane = tid & 63;
  const int quad = lane >> 4, l16 = lane & 15;
  const int oldS = (u + 1) & 1;

  if (role < 224) {
    const int l = (role < 32) ? 0 : ((role < 96) ? 1 : 2);
    const int nt = role - ((l == 0) ? 0 : ((l == 1) ? 32 : 96));
    const int t = u - 2 * l;
    if (t < 0 || t >= 128) return;
    const int H = 512 << l;

    f32x4 acc[2][2] = {};
    if (l == 0) {
      gemm_diag(p.xb + (size_t)t * 512 + (size_t)mh * 64 * 65536, 65536, 4,
                p.hb[0][oldS] + (size_t)mh * 64 * 512, 512, 4, p.wihzr0, 512,
                p.whhzr[0], 512, nt * 32, As, Bs, acc);
    } else {
      gemm_diag(p.hb[l][oldS] + (size_t)mh * 64 * H, (size_t)H, H >> 7,
                (const unsigned short*)0, 0, 0, p.whhzr[l], (size_t)H,
                (const unsigned short*)0, 0, nt * 32, As, Bs, acc);
    }

    const float* hfo = p.hf[l][oldS];
    const float* gil = (l == 0) ? (const float*)0 : p.gi[l][t & 1];
#pragma unroll
    for (int ni = 0; ni < 2; ++ni) {
      const int colg = nt * 32 + ni * 16 + l16;
      const float bv = p.bias[l][colg];
      const bool isz = colg < H;  // uniform per block (32 | H)
      const int j = isz ? colg : colg - H;
#pragma unroll
      for (int mi = 0; mi < 2; ++mi)
#pragma unroll
        for (int r = 0; r < 4; ++r) {
          const int row = mh * 64 + wave * 32 + mi * 16 + quad * 4 + r;
          float v = acc[mi][ni][r] + bv;
          if (l) v += gil[(size_t)row * 3 * H + colg];
          float s = sigmoidf_(v);
          if (isz)
            p.zb[l][(size_t)row * H + j] = s;
          else
            p.rh[l][(size_t)row * H + j] = f2b(s * hfo[(size_t)row * H + j]);
        }
    }
  } else {
    // gi1: gi(1, tg=u-1) = h0(tg) @ WihF[1]^T (raw). Consumed zr(1,tg) @u+1.
    const int g = role - 224;  // 0..95
    const int tg = u - 1;
    if (tg < 0 || tg >= 128) return;
    f32x4 acc[2][2] = {};
    gemm_diag(p.hb[0][oldS] + (size_t)mh * 64 * 512, 512, 4,
              (const unsigned short*)0, 0, 0, p.wihF[1], 512,
              (const unsigned short*)0, 0, g * 32, As, Bs, acc);
    float* gd = p.gi[1][tg & 1];
#pragma unroll
    for (int ni = 0; ni < 2; ++ni)
#pragma unroll
      for (int mi = 0; mi < 2; ++mi)
#pragma unroll
        for (int rr = 0; rr < 4; ++rr) {
          int row = mh * 64 + wave * 32 + mi * 16 + quad * 4 + rr;
          int colg = g * 32 + ni * 16 + l16;
          gd[(size_t)row * 3072 + colg] = acc[mi][ni][rr];
        }
  }
}

// ---- n launch: n-gates + gi2. Grid 608 = 2*(112+192). --------------------
__global__ __launch_bounds__(128) void diag_n(DiagP p, int u) {
  __shared__ unsigned short As[2 * 8192], Bs[2 * 4096];
  const int blk = blockIdx.x;
  const int mh = (blk >= 304) ? 1 : 0;
  const int role = blk - 304 * mh;
  const int tid = threadIdx.x, wave = tid >> 6, lane = tid & 63;
  const int quad = lane >> 4, l16 = lane & 15;
  const int oldS = (u + 1) & 1, newS = u & 1;

  if (role < 112) {
    const int l = (role < 16) ? 0 : ((role < 48) ? 1 : 2);
    const int nt = role - ((l == 0) ? 0 : ((l == 1) ? 16 : 48));
    const int t = u - 2 * l;
    if (t < 0 || t >= 128) return;
    const int H = 512 << l;
    const int outoff = (l == 0) ? 0 : ((l == 1) ? 512 : 1536);

    f32x4 acc[2][2] = {};
    if (l == 0) {
      gemm_diag(p.xb + (size_t)t * 512 + (size_t)mh * 64 * 65536, 65536, 4,
                p.rh[0] + (size_t)mh * 64 * 512, 512, 4, p.wihn0, 512,
                p.whhn[0], 512, nt * 32, As, Bs, acc);
    } else {
      gemm_diag(p.rh[l] + (size_t)mh * 64 * H, (size_t)H, H >> 7,
                (const unsigned short*)0, 0, 0, p.whhn[l], (size_t)H,
                (const unsigned short*)0, 0, nt * 32, As, Bs, acc);
    }

    const float* hfo = p.hf[l][oldS];
    float* hfn = p.hf[l][newS];
    unsigned short* hbn = p.hb[l][newS];
    const float* gil =
        (l == 0) ? (const float*)0 : (p.gi[l][t & 1] + 2 * H);  // n chunk
#pragma unroll
    for (int ni = 0; ni < 2; ++ni) {
      const int colg = nt * 32 + ni * 16 + l16;
      const float bv = p.bias[l][2 * H + colg];
#pragma unroll
      for (int mi = 0; mi < 2; ++mi)
#pragma unroll
        for (int r = 0; r < 4; ++r) {
          const int row = mh * 64 + wave * 32 + mi * 16 + quad * 4 + r;
          float v = acc[mi][ni][r] + bv;
          if (l) v += gil[(size_t)row * 3 * H + colg];
          float nv = tanhf_(v);
          size_t idx = (size_t)row * H + colg;
          float z = p.zb[l][idx];
          float hn = (1.0f - z) * nv + z * hfo[idx];
          hfn[idx] = hn;
          hbn[idx] = f2b(hn);
          p.out[(size_t)row * 3584 + outoff + colg] +=
              p.mask[row * 128 + t] * hn;
        }
    }
  } else {
    // gi2: gi(2, tg=u-3) = h1(tg) @ WihF[2]^T (raw). Consumed zr(2,tg) @u+1.
    const int g = role - 112;  // 0..191
    const int tg = u - 3;
    if (tg < 0 || tg >= 128) return;
    f32x4 acc[2][2] = {};
    gemm_diag(p.hb[1][oldS] + (size_t)mh * 64 * 1024, 1024, 8,
              (const unsigned short*)0, 0, 0, p.wihF[2], 1024,
              (const unsigned short*)0, 0, g * 32, As, Bs, acc);
    float* gd = p.gi[2][tg & 1];
#pragma unroll
    for (int ni = 0; ni < 2; ++ni)
#pragma unroll
      for (int mi = 0; mi < 2; ++mi)
#pragma unroll
        for (int rr = 0; rr < 4; ++rr) {
          int row = mh * 64 + wave * 32 + mi * 16 + quad * 4 + rr;
          int colg = g * 32 + ni * 16 + l16;
          gd[(size_t)row * 6144 + colg] = acc[mi][ni][rr];
        }
  }
}

__global__ void cast_kernel(const float* __restrict__ src,
                            unsigned short* __restrict__ dst, int n) {
  int i = blockIdx.x * 256 + threadIdx.x;
  if (i < n) dst[i] = f2b(src[i]);
}

extern "C" void kernel_launch(void* const* d_in, const int* in_sizes, int n_in,
                              void* d_out, int out_size, void* d_ws,
                              size_t ws_size, hipStream_t stream) {
  const int B = 128, T = 128, I = 512;
  const int Hs[3] = {512, 1024, 2048};

  const float* x = (const float*)d_in[0];
  const float* mask = (const float*)d_in[1];
  const float* Wih[3] = {(const float*)d_in[2], (const float*)d_in[5],
                         (const float*)d_in[8]};
  const float* Whh[3] = {(const float*)d_in[3], (const float*)d_in[6],
                         (const float*)d_in[9]};
  const float* bias[3] = {(const float*)d_in[4], (const float*)d_in[7],
                          (const float*)d_in[10]};

  char* ws = (char*)d_ws;
  size_t off = 0;
  auto alloc = [&](size_t bytes) -> void* {
    void* p = ws + off;
    off = (off + bytes + 255) & ~(size_t)255;
    return p;
  };

  unsigned short* xb = (unsigned short*)alloc((size_t)B * T * I * 2);
  unsigned short *wihb[3], *whhb[3];
  for (int l = 0; l < 3; ++l) {
    int inl = (l == 0) ? I : Hs[l - 1];
    wihb[l] = (unsigned short*)alloc((size_t)3 * Hs[l] * inl * 2);
    whhb[l] = (unsigned short*)alloc((size_t)3 * Hs[l] * Hs[l] * 2);
  }
  size_t hstart = off;
  DiagP p;
  for (int l = 0; l < 3; ++l)
    for (int sl = 0; sl < 2; ++sl)
      p.hf[l][sl] = (float*)alloc((size_t)B * Hs[l] * 4);
  for (int l = 0; l < 3; ++l)
    for (int sl = 0; sl < 2; ++sl)
      p.hb[l][sl] = (unsigned short*)alloc((size_t)B * Hs[l] * 2);
  size_t hend = off;
  for (int l = 0; l < 3; ++l) p.zb[l] = (float*)alloc((size_t)B * Hs[l] * 4);
  for (int l = 0; l < 3; ++l)
    p.rh[l] = (unsigned short*)alloc((size_t)B * Hs[l] * 2);
  p.gi[0][0] = p.gi[0][1] = (float*)0;
  for (int l = 1; l < 3; ++l)
    for (int sl = 0; sl < 2; ++sl)
      p.gi[l][sl] = (float*)alloc((size_t)B * 3 * Hs[l] * 4);
  (void)ws_size;

  p.xb = xb;
  p.wihzr0 = wihb[0];
  p.wihn0 = wihb[0] + (size_t)2 * Hs[0] * I;
  for (int l = 0; l < 3; ++l) {
    p.wihF[l] = wihb[l];
    p.whhzr[l] = whhb[l];
    p.whhn[l] = whhb[l] + (size_t)2 * Hs[l] * Hs[l];
    p.bias[l] = bias[l];
  }
  p.mask = mask;
  p.out = (float*)d_out;

  auto cast = [&](const float* s, unsigned short* d, int n) {
    cast_kernel<<<(n + 255) / 256, 256, 0, stream>>>(s, d, n);
  };
  cast(x, xb, B * T * I);
  for (int l = 0; l < 3; ++l) {
    int inl = (l == 0) ? I : Hs[l - 1];
    cast(Wih[l], wihb[l], 3 * Hs[l] * inl);
    cast(Whh[l], whhb[l], 3 * Hs[l] * Hs[l]);
  }
  hipMemsetAsync(ws + hstart, 0, hend - hstart, stream);
  hipMemsetAsync(d_out, 0, (size_t)out_size * 4, stream);

  // ---- diagonal scan: tick u covers layer l at t = u - 2l ----
  // gi1(tg=u-1) rides in zr(u); gi2(tg=u-3) rides in n(u).
  for (int u = 0; u < 132; ++u) {
    diag_zr<<<640, 128, 0, stream>>>(p, u);
    diag_n<<<608, 128, 0, stream>>>(p, u);
  }
}